// Round 6
// baseline (324.203 us; speedup 1.0000x reference)
//
#include <hip/hip_runtime.h>
#include <math.h>

#define C  2048
#define L  4096
#define L2 2048
#define CW3 6144  // C*3

// ---- d_ws layout (float offsets) ----
constexpr size_t OFF_RS_A = 0;      // 2048
constexpr size_t OFF_RQ_A = 2048;   // 2048
constexpr size_t OFF_RS_B = 4096;   // 2048
constexpr size_t OFF_RQ_B = 6144;   // 2048
constexpr size_t OFF_SCAL = 8192;   // 16: [0]=meanA [1]=coefA [2]=meanB [3]=coefB [4]=sum(fc_b)
constexpr size_t OFF_S    = 8208;   // 2048
constexpr size_t OFF_U    = 10256;  // 6144
constexpr size_t OFF_MIX  = 16400;  // 2048
// total 18448 floats = 73.8 KB

// ---- contention-free partials in d_out (fully overwritten by w7) ----
constexpr size_t SC_CWP  = 0;        // [32][2048]  = 65536
constexpr size_t SC_GP   = 65536;    // [32][6144]  = 196608 -> ends 262144
constexpr size_t SC_HP   = 262144;   // [32][6144]  -> ends 458752
constexpr size_t SC_VP   = 458752;   // [16][2048]  = 32768  -> ends 491520
constexpr size_t SC_O2P  = 491520;   // [16][2048]  -> ends 524288  (< 8388608)

__device__ __forceinline__ float wredf(float v) {
#pragma unroll
  for (int o = 32; o; o >>= 1) v += __shfl_down(v, o, 64);
  return v;
}
__device__ __forceinline__ double wredd(double v) {
#pragma unroll
  for (int o = 32; o; o >>= 1) v += __shfl_down(v, o, 64);
  return v;
}
__device__ __forceinline__ float sigm(float x) { return 1.f / (1.f + expf(-x)); }
__device__ __forceinline__ float simam1(float x, float m, float cf) {
  float d = x - m;
  float y = d * d * cf + 0.5f;
  return x * (1.f + 1.f / (1.f + expf(-y)));
}

// ===== w1: rowstats (4096 blocks) | cw partials (256 blocks), no atomics =====
__global__ void w1(const float* __restrict__ A, const float* __restrict__ B,
                   const float* __restrict__ fc_w, float* __restrict__ ws,
                   float* __restrict__ sc) {
  int u = blockIdx.x;
  int tid = threadIdx.x;
  if (u < 4096) {
    __shared__ float sm[8];
    const float* src = (u < 2048) ? A : B;
    int row = u & 2047;
    const float4* p = (const float4*)(src + (size_t)row * L);
    float s = 0.f, q = 0.f;
#pragma unroll
    for (int i = tid; i < L / 4; i += 256) {
      float4 v = p[i];
      s += (v.x + v.y) + (v.z + v.w);
      q += (v.x * v.x + v.y * v.y) + (v.z * v.z + v.w * v.w);
    }
    s = wredf(s); q = wredf(q);
    int lane = tid & 63, wv = tid >> 6;
    if (!lane) { sm[wv] = s; sm[4 + wv] = q; }
    __syncthreads();
    if (!tid) {
      float* rs = ws + ((u < 2048) ? OFF_RS_A : OFF_RS_B);
      float* rq = ws + ((u < 2048) ? OFF_RQ_A : OFF_RQ_B);
      rs[row] = sm[0] + sm[1] + sm[2] + sm[3];
      rq[row] = sm[4] + sm[5] + sm[6] + sm[7];
    }
  } else {
    int cb = u - 4096;            // 0..255
    int rg = cb >> 3;             // 0..31 (64 rows each)
    int col = (cb & 7) * 256 + tid;
    const float* p = fc_w + (size_t)rg * 64 * C + col;
    float acc = 0.f;
#pragma unroll 8
    for (int k = 0; k < 64; ++k) acc += p[(size_t)k * C];
    (sc + SC_CWP)[(size_t)rg * C + col] = acc;   // plain store
  }
}

// ===== w2: s (2048) + scalars (1) =====
__global__ void w2(const float* __restrict__ fc_w, const float* __restrict__ fc_b,
                   float* __restrict__ ws) {
  int u = blockIdx.x;
  int tid = threadIdx.x;
  int lane = tid & 63, wv = tid >> 6;
  if (u < 2048) {
    __shared__ float sl[4];
    const float4* w = (const float4*)(fc_w + (size_t)u * C);
    const float4* rx = (const float4*)(ws + OFF_RS_A);
    float acc = 0.f;
#pragma unroll
    for (int i = tid; i < C / 4; i += 256) {
      float4 a = w[i], r = rx[i];
      acc += a.x * r.x + a.y * r.y + a.z * r.z + a.w * r.w;
    }
    acc = wredf(acc);
    if (!lane) sl[wv] = acc;
    __syncthreads();
    if (!tid)
      (ws + OFF_S)[u] = 0.5f * (sl[0] + sl[1] + sl[2] + sl[3]) + (float)L2 * fc_b[u];
  } else {
    __shared__ double sd[5];
    const float* arr = ws + (wv == 0 ? OFF_RS_A : wv == 1 ? OFF_RQ_A
                                                          : wv == 2 ? OFF_RS_B : OFF_RQ_B);
    double acc = 0.0, accb = 0.0;
    for (int i = lane; i < 2048; i += 64) {
      acc += (double)arr[i];
      if (wv == 0) accb += (double)fc_b[i];
    }
    acc = wredd(acc);
    if (wv == 0) accb = wredd(accb);
    if (!lane) { sd[wv] = acc; if (wv == 0) sd[4] = accb; }
    __syncthreads();
    if (!tid) {
      const double N = (double)C * (double)L, n = N - 1.0;
      double dA = sd[1] - sd[0] * sd[0] / N;
      double dB = sd[3] - sd[2] * sd[2] / N;
      float* s = ws + OFF_SCAL;
      s[0] = (float)(sd[0] / N);
      s[1] = (float)(1.0 / (4.0 * (dA / n + 1e-4)));
      s[2] = (float)(sd[2] / N);
      s[3] = (float)(1.0 / (4.0 * (dB / n + 1e-4)));
      s[4] = (float)sd[4];
    }
  }
}

// ===== w3: reduce cw slice in LDS, then g/h partials (no atomics) =====
// grid: 24 colchunks x 32 rowgroups (64 rows) = 768 blocks
__global__ void w3(const float* __restrict__ conv1_w, const float* __restrict__ ws,
                   float* __restrict__ sc) {
  __shared__ float lcw[64], ls[64];
  int u = blockIdx.x;
  int tid = threadIdx.x;
  int cc = u % 24, rg = u / 24;
  int col = cc * 256 + tid;
  int i0 = rg * 64;
  if (tid < 64) {
    float a = 0.f;
#pragma unroll 8
    for (int p = 0; p < 32; ++p) a += (sc + SC_CWP)[(size_t)p * C + i0 + tid];
    lcw[tid] = a;
    ls[tid] = (ws + OFF_S)[i0 + tid];
  }
  __syncthreads();
  const float* base = conv1_w + (size_t)i0 * CW3 + col;
  float ag = 0.f, ah = 0.f;
#pragma unroll 8
  for (int k = 0; k < 64; ++k) {
    float wv = base[(size_t)k * CW3];
    ag += lcw[k] * wv;
    ah += ls[k] * wv;
  }
  (sc + SC_GP)[(size_t)rg * CW3 + col] = ag;
  (sc + SC_HP)[(size_t)rg * CW3 + col] = ah;
}

// ===== w4: reduce g/h slice in LDS + v/o2 partials from raw insum =====
// grid: 8 k-tiles x 16 ch-groups (128 ch) = 128 blocks; slices contention-free
__global__ void w4(const float* __restrict__ insum, float* __restrict__ sc) {
  __shared__ float gsh[384], hsh[384];
  int u = blockIdx.x;
  int tid = threadIdx.x;
  int kb = u & 7, cg = u >> 3;    // cg 0..15
  int c0 = cg * 128;
  int k = kb * 256 + tid;
  for (int idx = tid; idx < 384; idx += 256) {
    float ag = 0.f, ah = 0.f;
#pragma unroll 8
    for (int p = 0; p < 32; ++p) {
      ag += (sc + SC_GP)[(size_t)p * CW3 + c0 * 3 + idx];
      ah += (sc + SC_HP)[(size_t)p * CW3 + c0 * 3 + idx];
    }
    gsh[idx] = ag;
    hsh[idx] = ah;
  }
  __syncthreads();
  float accv = 0.f, acco = 0.f;
  for (int c = 0; c < 128; ++c) {
    const float* row = insum + (size_t)(c0 + c) * L;
    float2 bm = *(const float2*)(row + 2 * k);
    float xc = (bm.x + bm.y) * 0.5f;
    float xl = 0.f, xr = 0.f;
    if (k > 0) {
      float2 am = *(const float2*)(row + 2 * k - 2);
      xl = (am.x + am.y) * 0.5f;
    }
    if (k < L2 - 1) {
      float2 dm = *(const float2*)(row + 2 * k + 2);
      xr = (dm.x + dm.y) * 0.5f;
    }
    accv += gsh[c * 3] * xl + gsh[c * 3 + 1] * xc + gsh[c * 3 + 2] * xr;
    acco += hsh[c * 3] * xl + hsh[c * 3 + 1] * xc + hsh[c * 3 + 2] * xr;
  }
  (sc + SC_VP)[(size_t)cg * L2 + k] = accv;
  (sc + SC_O2P)[(size_t)cg * L2 + k] = acco;
}

// ===== w5: U correlations; v assembled from 16 slices (+bias) in LDS =====
__global__ void w5(const float* __restrict__ input, const float* __restrict__ sc,
                   float* __restrict__ ws) {
  __shared__ float vsh[2050];
  __shared__ float s12[12];
  int u = blockIdx.x;
  int tid = threadIdx.x;
  float sb = (ws + OFF_SCAL)[4];
  if (tid == 0) { vsh[0] = 0.f; vsh[2049] = 0.f; }
  for (int j = tid; j < L2; j += 256) {
    float a = sb;
#pragma unroll 8
    for (int sl = 0; sl < 16; ++sl) a += (sc + SC_VP)[(size_t)sl * L2 + j];
    vsh[1 + j] = a;
  }
  __syncthreads();
  const float* row = input + (size_t)u * L;
  float a0 = 0.f, a1 = 0.f, a2 = 0.f;
#pragma unroll
  for (int j = tid; j < L2; j += 256) {
    float2 ab = *(const float2*)(row + 2 * j);
    float xm = (ab.x + ab.y) * 0.5f;
    a0 += xm * vsh[j + 2];
    a1 += xm * vsh[j + 1];
    a2 += xm * vsh[j];
  }
  a0 = wredf(a0); a1 = wredf(a1); a2 = wredf(a2);
  int lane = tid & 63, wv = tid >> 6;
  if (!lane) { s12[wv] = a0; s12[4 + wv] = a1; s12[8 + wv] = a2; }
  __syncthreads();
  if (!tid) {
    (ws + OFF_U)[u * 3 + 0] = s12[0] + s12[1] + s12[2] + s12[3];
    (ws + OFF_U)[u * 3 + 1] = s12[4] + s12[5] + s12[6] + s12[7];
    (ws + OFF_U)[u * 3 + 2] = s12[8] + s12[9] + s12[10] + s12[11];
  }
}

// ===== w6: out1 + mix (o2 summed from 16 slices) =====
__global__ void w6(const float* __restrict__ conv1_w, const float* __restrict__ mix_w,
                   const float* __restrict__ sc, float* __restrict__ ws) {
  __shared__ float sl[4];
  int u = blockIdx.x;
  int tid = threadIdx.x;
  const float4* w4p = (const float4*)(conv1_w + (size_t)u * CW3);
  const float4* u4 = (const float4*)(ws + OFF_U);
  float acc = 0.f;
#pragma unroll
  for (int m = tid; m < CW3 / 4; m += 256) {
    float4 wv = w4p[m], uv = u4[m];
    acc += wv.x * uv.x + wv.y * uv.y + wv.z * uv.z + wv.w * uv.w;
  }
  acc = wredf(acc);
  int lane = tid & 63, wv = tid >> 6;
  if (!lane) sl[wv] = acc;
  __syncthreads();
  if (!tid) {
    float o2r = 0.f;
#pragma unroll 8
    for (int slc = 0; slc < 16; ++slc) o2r += (sc + SC_O2P)[(size_t)slc * L2 + u];
    float mfv = sigm(mix_w[0]);
    float o1 = sigm(sl[0] + sl[1] + sl[2] + sl[3]);
    float o2 = sigm(o2r);
    (ws + OFF_MIX)[u] = o1 * mfv + o2 * (1.f - mfv);
  }
}

// ===== w7: per-row mid-tap gate + final elementwise (overwrites d_out) =====
__global__ void w7(const float* __restrict__ input, const float* __restrict__ insum,
                   const float* __restrict__ conv1_w, float* __restrict__ out,
                   const float* __restrict__ ws) {
  __shared__ float sl[4];
  __shared__ float shov;
  int u = blockIdx.x;
  int tid = threadIdx.x;
  const float4* w4p = (const float4*)(conv1_w + (size_t)u * CW3);
  const float4* m4 = (const float4*)(ws + OFF_MIX);
  float acc = 0.f;
#pragma unroll
  for (int p = tid; p < 512; p += 256) {
    float4 f0 = w4p[3 * p], f1 = w4p[3 * p + 1], f2 = w4p[3 * p + 2];
    float4 m = m4[p];
    acc += f0.y * m.x + f1.x * m.y + f1.w * m.z + f2.z * m.w;
  }
  acc = wredf(acc);
  int lane = tid & 63, wv = tid >> 6;
  if (!lane) sl[wv] = acc;
  __syncthreads();
  if (!tid) shov = sigm(sl[0] + sl[1] + sl[2] + sl[3]);
  __syncthreads();
  float ovc = shov;
  const float* scal = ws + OFF_SCAL;
  float mA = scal[0], cA = scal[1], mB = scal[2], cB = scal[3];
  size_t base = (size_t)u * L;
  const float4* pa = (const float4*)(input + base);
  const float4* pb = (const float4*)(insum + base);
  float4* po = (float4*)(out + base);
#pragma unroll
  for (int i = tid; i < L / 4; i += 256) {
    float4 a = pa[i], b = pb[i], r;
    r.x = (simam1(a.x, mA, cA) * 0.6f + simam1(b.x, mB, cB) * 0.4f) * ovc;
    r.y = (simam1(a.y, mA, cA) * 0.6f + simam1(b.y, mB, cB) * 0.4f) * ovc;
    r.z = (simam1(a.z, mA, cA) * 0.6f + simam1(b.z, mB, cB) * 0.4f) * ovc;
    r.w = (simam1(a.w, mA, cA) * 0.6f + simam1(b.w, mB, cB) * 0.4f) * ovc;
    po[i] = r;
  }
}

extern "C" void kernel_launch(void* const* d_in, const int* in_sizes, int n_in,
                              void* d_out, int out_size, void* d_ws, size_t ws_size,
                              hipStream_t stream) {
  const float* input   = (const float*)d_in[0];
  const float* insum   = (const float*)d_in[1];
  const float* conv1_w = (const float*)d_in[2];
  const float* fc_w    = (const float*)d_in[3];
  const float* fc_b    = (const float*)d_in[4];
  const float* mix_w   = (const float*)d_in[5];
  float* out = (float*)d_out;
  float* ws  = (float*)d_ws;
  float* sc  = out;  // partials staged in d_out; w7 overwrites everything

  dim3 b(256);
  w1<<<4352, b, 0, stream>>>(input, insum, fc_w, ws, sc);
  w2<<<2049, b, 0, stream>>>(fc_w, fc_b, ws);
  w3<<<768, b, 0, stream>>>(conv1_w, ws, sc);
  w4<<<128, b, 0, stream>>>(insum, sc);
  w5<<<2048, b, 0, stream>>>(input, sc, ws);
  w6<<<2048, b, 0, stream>>>(conv1_w, mix_w, sc, ws);
  w7<<<2048, b, 0, stream>>>(input, insum, conv1_w, out, ws);
}